// Round 3
// baseline (79.166 us; speedup 1.0000x reference)
//
#include <hip/hip_runtime.h>

// GausLJLayer: per-element LJ (3) + Gaussian (4) energy/force.
// Memory-bound (403 MB @ ~96 B/elem). Persistent grid-stride kernel,
// double-buffered LDS param staging via global_load_lds(16B): stage tile k+1
// while computing tile k; one __syncthreads (vmcnt(0)+barrier) per tile.

constexpr int BLOCK   = 256;
constexpr int NPAR    = 21;                    // 3*3 LJ + 4*3 Gauss
constexpr int TILE_F4 = BLOCK * NPAR / 4;      // 1344 float4 = 21504 B / tile
constexpr int GRID    = 768;                   // 3 blocks/CU x 256 CU

__device__ __forceinline__ void stage_tile(float4* dst, const float* __restrict__ param,
                                           long long base, int n, int t)
{
    if (base + BLOCK <= (long long)n) {
        // fast path: contiguous, 16B-aligned range of TILE_F4 float4s
        const float4* g4 = (const float4*)(param + base * NPAR);
        const int wbase = t & ~63;             // wave-uniform LDS base
        #pragma unroll
        for (int j = 0; j < 6; ++j) {
            const int idx = j * 256 + t;
            if (idx < TILE_F4) {               // wave-uniform predicate
                __builtin_amdgcn_global_load_lds(
                    (const __attribute__((address_space(1))) void*)(g4 + idx),
                    (__attribute__((address_space(3))) void*)(dst + j * 256 + wbase),
                    16, 0, 0);
            }
        }
    } else {
        // tail tile: guarded scalar staging
        float* d = (float*)dst;
        const long long gbase = base * NPAR;
        const long long ptot  = (long long)n * NPAR;
        for (int j = 0; j < NPAR; ++j) {
            long long g = gbase + j * BLOCK + t;
            if (g < ptot) d[j * BLOCK + t] = param[g];
        }
    }
}

__global__ __launch_bounds__(BLOCK, 3)
void gauslj_kernel(const float* __restrict__ distance,
                   const float* __restrict__ param,
                   float* __restrict__ out,    // [0..n) energies, [n..2n) forces
                   int n)
{
    __shared__ float4 buf[2][TILE_F4];         // 43008 B -> 3 blocks/CU

    const int t = threadIdx.x;
    const int T = (n + BLOCK - 1) / BLOCK;     // total tiles

    int tile = blockIdx.x;
    if (tile >= T) return;

    stage_tile(buf[0], param, (long long)tile * BLOCK, n, t);
    int cur = 0;

    for (; tile < T; tile += GRID) {
        __syncthreads();                       // vmcnt(0)+barrier: buf[cur] ready,
                                               // buf[cur^1] free to overwrite
        const long long base = (long long)tile * BLOCK;
        const long long i    = base + t;
        const float d = (i < n) ? distance[i] : 1.0f;

        const int nxt = tile + GRID;
        if (nxt < T)                           // prefetch next tile into other buf
            stage_tile(buf[cur ^ 1], param, (long long)nxt * BLOCK, n, t);

        const float inv_d = __builtin_amdgcn_rcpf(d);
        const float id2   = inv_d * inv_d;
        const float id6   = id2 * id2 * id2;
        const float id7   = id6 * inv_d;
        const float id12  = id6 * id6;
        const float id13  = id12 * inv_d;

        const float* p = (const float*)buf[cur] + t * NPAR;  // gcd(21,32)=1: conflict-free

        float e = 0.0f, f = 0.0f;

        // LJ: p[3k+1]=c, p[3k+2]=sigma (p[3k] unused, matches reference)
        #pragma unroll
        for (int k = 0; k < 3; ++k) {
            const float c   = p[3 * k + 1];
            const float s   = p[3 * k + 2];
            const float s2  = s * s;
            const float s6  = s2 * s2 * s2;
            const float s12 = s6 * s6;
            e += 4.0f * c * (s12 * id12 - s6 * id6);
            f += -4.0f * c * (4.0f * s6 * id7 - 12.0f * s12 * id13);
        }

        // Gaussian: p[9+3k]=amplitude, +1=mean, +2=stddev
        #pragma unroll
        for (int k = 0; k < 4; ++k) {
            const float a       = p[9 + 3 * k + 0];
            const float mu      = p[9 + 3 * k + 1];
            const float sd      = p[9 + 3 * k + 2];
            const float dm      = d - mu;
            const float inv_sd2 = __builtin_amdgcn_rcpf(sd * sd);
            const float ex      = __expf(-0.5f * dm * dm * inv_sd2);
            e += a * ex;
            f += -(a * dm * ex) * (dm * dm) * inv_sd2 * inv_sd2;
        }

        if (i < n) {
            __builtin_nontemporal_store(e, &out[i]);
            __builtin_nontemporal_store(f, &out[n + i]);
        }
        cur ^= 1;
    }
}

extern "C" void kernel_launch(void* const* d_in, const int* in_sizes, int n_in,
                              void* d_out, int out_size, void* d_ws, size_t ws_size,
                              hipStream_t stream) {
    const float* distance = (const float*)d_in[0];
    const float* param    = (const float*)d_in[1];
    float* out            = (float*)d_out;
    const int n = in_sizes[0];

    const int T = (n + BLOCK - 1) / BLOCK;
    const int grid = (T < GRID) ? T : GRID;
    gauslj_kernel<<<grid, BLOCK, 0, stream>>>(distance, param, out, n);
}